// Round 1
// baseline (408.129 us; speedup 1.0000x reference)
//
#include <hip/hip_runtime.h>
#include <type_traits>

// Problem constants (ExaoneFlashAttention): B=4, S=1024, T=4096, D_MODEL=2048,
// H=32, KVH=8, HD=64, GROUPS=4, SCALE=1/8. All bf16 MFMA, f32 accum.

typedef __bf16 bf16x8 __attribute__((ext_vector_type(8)));
typedef float f32x4 __attribute__((ext_vector_type(4)));
typedef unsigned short u16;
typedef unsigned int u32;

#define DEVI __device__ __forceinline__

DEVI u16 f2bf(float f) {           // RNE f32->bf16 (finite inputs)
  u32 u = __builtin_bit_cast(u32, f);
  u += 0x7FFF + ((u >> 16) & 1);
  return (u16)(u >> 16);
}
DEVI float bf2f(u16 h) { return __builtin_bit_cast(float, (u32)h << 16); }

// async global->LDS, 16B per lane. LDS dest must be wave-uniform base + lane*16.
DEVI void ld16_lds(const void* g, void* l) {
  __builtin_amdgcn_global_load_lds((const __attribute__((address_space(1))) u32*)g,
                                   (__attribute__((address_space(3))) u32*)l, 16, 0, 0);
}

// ---------------- elementwise f32 -> bf16 ----------------
__global__ __launch_bounds__(256) void convert_f32_bf16(const float* __restrict__ src,
                                                        u16* __restrict__ dst, int n4) {
  int i = blockIdx.x * 256 + threadIdx.x;
  if (i >= n4) return;
  float4 v = ((const float4*)src)[i];
  ushort4 o;
  o.x = f2bf(v.x); o.y = f2bf(v.y); o.z = f2bf(v.z); o.w = f2bf(v.w);
  ((ushort4*)dst)[i] = o;
}

// ---------------- transpose + convert: src RxC f32 -> dst CxR bf16 ----------------
__global__ __launch_bounds__(256) void trans_f32_bf16(const float* __restrict__ src,
                                                      u16* __restrict__ dst, int R, int C) {
  __shared__ float tile[32][33];
  int c0 = blockIdx.x * 32, r0 = blockIdx.y * 32;
  int tx = threadIdx.x & 31, ty = threadIdx.x >> 5;   // ty 0..7
#pragma unroll
  for (int i = 0; i < 32; i += 8)
    tile[ty + i][tx] = src[(size_t)(r0 + ty + i) * C + (c0 + tx)];
  __syncthreads();
#pragma unroll
  for (int i = 0; i < 32; i += 8)
    dst[(size_t)(c0 + ty + i) * R + (r0 + tx)] = f2bf(tile[tx][ty + i]);
}

// ---------------- GEMM: C(MxN) = A(MxK) * BT(NxK)^T, bf16 in, f32 acc ----------------
// 128x128 tile, 256 thr (4 waves, each 64x64 = 4x4 MFMA tiles), BK=32.
// LDS staged via global_load_lds(16B); 16B chunks XOR-swizzled by row to kill
// bank conflicts on ds_read_b128 fragment loads.
template <typename OutT>
__global__ __launch_bounds__(256) void gemm_bt(const u16* __restrict__ A, const u16* __restrict__ BT,
                                               OutT* __restrict__ C, int M, int N, int K) {
  __shared__ u16 As[128 * 32];
  __shared__ u16 Bs[128 * 32];
  const int tid = threadIdx.x;
  const int lane = tid & 63, wave = tid >> 6;
  const int quad = lane >> 4, l16 = lane & 15;
  const int m0 = blockIdx.y * 128, n0 = blockIdx.x * 128;
  const int wr = (wave >> 1) * 64, wc = (wave & 1) * 64;

  f32x4 acc[4][4] = {};

  const int srow = tid >> 2;                    // 0..63
  const int sc = (tid & 3) ^ (srow & 3);        // swizzled source chunk (16B units)
  const u16* Ag0 = A + (size_t)(m0 + srow) * K + sc * 8;
  const u16* Ag1 = A + (size_t)(m0 + srow + 64) * K + sc * 8;
  const u16* Bg0 = BT + (size_t)(n0 + srow) * K + sc * 8;
  const u16* Bg1 = BT + (size_t)(n0 + srow + 64) * K + sc * 8;
  u16* Ad0 = &As[tid * 8];            // lds byte = tid*16 (wave-contiguous)
  u16* Ad1 = &As[tid * 8 + 64 * 32];
  u16* Bd0 = &Bs[tid * 8];
  u16* Bd1 = &Bs[tid * 8 + 64 * 32];

  for (int k0 = 0; k0 < K; k0 += 32) {
    __syncthreads();
    ld16_lds(Ag0 + k0, Ad0);
    ld16_lds(Ag1 + k0, Ad1);
    ld16_lds(Bg0 + k0, Bd0);
    ld16_lds(Bg1 + k0, Bd1);
    __syncthreads();   // compiler emits vmcnt(0) drain before s_barrier

    bf16x8 af[4], bfr[4];
#pragma unroll
    for (int i = 0; i < 4; i++) {
      int ar = wr + i * 16 + l16;
      af[i] = *(const bf16x8*)&As[ar * 32 + (quad ^ (ar & 3)) * 8];
      int br = wc + i * 16 + l16;
      bfr[i] = *(const bf16x8*)&Bs[br * 32 + (quad ^ (br & 3)) * 8];
    }
#pragma unroll
    for (int i = 0; i < 4; i++)
#pragma unroll
      for (int j = 0; j < 4; j++)
        acc[i][j] = __builtin_amdgcn_mfma_f32_16x16x32_bf16(af[i], bfr[j], acc[i][j], 0, 0, 0);
  }

  // epilogue: C/D layout col=lane&15, row=quad*4+r (m89/m91-verified)
#pragma unroll
  for (int i = 0; i < 4; i++) {
    int row = m0 + wr + i * 16 + quad * 4;
#pragma unroll
    for (int j = 0; j < 4; j++) {
      int col = n0 + wc + j * 16 + l16;
#pragma unroll
      for (int r = 0; r < 4; r++) {
        size_t off = (size_t)(row + r) * N + col;
        if constexpr (sizeof(OutT) == 2) C[off] = f2bf(acc[i][j][r]);
        else C[off] = acc[i][j][r];
      }
    }
  }
}

// ---------------- RoPE in-place on QKV (bf16), Q heads 0..31, K heads 0..7 ----------------
__global__ __launch_bounds__(256) void rope_k(u16* __restrict__ qkv, const float* __restrict__ cs,
                                              const float* __restrict__ sn) {
  int idx = blockIdx.x * 256 + threadIdx.x;   // T*40*32 exactly
  int d = idx & 31;
  int rest = idx >> 5;
  int h = rest % 40;
  int t = rest / 40;
  int col = (h < 32) ? (h * 64 + d) : (2048 + (h - 32) * 64 + d);
  u16* p = qkv + (size_t)t * 3072 + col;
  float x1 = bf2f(p[0]), x2 = bf2f(p[32]);
  float c = cs[t * 32 + d], s = sn[t * 32 + d];
  p[0] = f2bf(x1 * c - x2 * s);
  p[32] = f2bf(x2 * c + x1 * s);
}

// ---------------- flash attention: grid (qt=8, h=32, b=4), 256 thr ----------------
// Per wave: 32 q-rows. QK^T and PV via 16x16x32 MFMA. P round-trips through
// per-wave-private LDS (C-layout -> A-layout). V staged transposed (swizzled).
// LDS = 32KB(P/Qstage) + 16KB(K) + 16KB(VT) = 64KB -> 2 blocks/CU.
__global__ __launch_bounds__(256, 2) void flash_attn(const u16* __restrict__ qkv,
                                                     u16* __restrict__ attn) {
  __shared__ u16 Ps[128 * 128];   // P tiles (also initial Q staging: 128x64 front)
  __shared__ u16 Ks[128 * 64];
  __shared__ u16 VT[64 * 128];

  const int tid = threadIdx.x;
  const int lane = tid & 63, wave = tid >> 6;
  const int quad = lane >> 4, l16 = lane & 15;
  const int qt = blockIdx.x, h = blockIdx.y, b = blockIdx.z;
  const int kvh = h >> 2;
  const size_t tokBase = (size_t)b * 1024;
  const int qcol = h * 64, kcol = 2048 + kvh * 64, vcol = 2560 + kvh * 64;

  // ---- stage Q tile (rows of 128B, 8 chunks, XOR-swizzled source chunk) ----
  {
    const int row = tid >> 3, pc = tid & 7, sc = pc ^ (row & 7);
#pragma unroll
    for (int i = 0; i < 4; i++) {
      const u16* g = qkv + (tokBase + qt * 128 + row + i * 32) * 3072 + qcol + sc * 8;
      ld16_lds(g, &Ps[tid * 8 + i * 2048]);
    }
  }
  __syncthreads();
  bf16x8 qf[2][2];
#pragma unroll
  for (int im = 0; im < 2; im++) {
    int row = wave * 32 + im * 16 + l16;
#pragma unroll
    for (int ks = 0; ks < 2; ks++) {
      int c = (ks * 4 + quad) ^ (row & 7);
      qf[im][ks] = *(const bf16x8*)&Ps[row * 64 + c * 8];
    }
  }

  float m_run[2][4], l_run[2][4];
  f32x4 o[2][4] = {};
#pragma unroll
  for (int im = 0; im < 2; im++)
#pragma unroll
    for (int r = 0; r < 4; r++) { m_run[im][r] = -3e38f; l_run[im][r] = 0.f; }

  for (int kt = 0; kt <= qt; kt++) {
    __syncthreads();   // prev-iter LDS reads done before restage
    // ---- stage K via global_load_lds (swizzled chunks) ----
    {
      const int row = tid >> 3, pc = tid & 7, sc = pc ^ (row & 7);
#pragma unroll
      for (int i = 0; i < 4; i++) {
        const u16* g = qkv + (tokBase + kt * 128 + row + i * 32) * 3072 + kcol + sc * 8;
        ld16_lds(g, &Ks[tid * 8 + i * 2048]);
      }
    }
    // ---- stage V transposed: VT[dd][kk], 16 chunks/row XOR-swizzled by dd&15 ----
#pragma unroll
    for (int i = 0; i < 4; i++) {
      int u = i * 256 + tid;
      int kk = u & 127, ch = u >> 7;   // ch 0..7 (8 dd per thread-load)
      uint4 vv = *(const uint4*)(qkv + (tokBase + kt * 128 + kk) * 3072 + vcol + ch * 8);
      const u16* pv = (const u16*)&vv;
#pragma unroll
      for (int j = 0; j < 8; j++) {
        int dd = ch * 8 + j;
        VT[dd * 128 + (((kk >> 3) ^ (dd & 15)) << 3) + (kk & 7)] = pv[j];
      }
    }
    __syncthreads();

    // ---- S = Q K^T (per wave: 2 m-tiles x 8 n-tiles x 2 k-steps) ----
    f32x4 s[2][8] = {};
#pragma unroll
    for (int ks = 0; ks < 2; ks++)
#pragma unroll
      for (int jn = 0; jn < 8; jn++) {
        int krow = jn * 16 + l16;
        int c = (ks * 4 + quad) ^ (krow & 7);
        bf16x8 kf = *(const bf16x8*)&Ks[krow * 64 + c * 8];
        s[0][jn] = __builtin_amdgcn_mfma_f32_16x16x32_bf16(qf[0][ks], kf, s[0][jn], 0, 0, 0);
        s[1][jn] = __builtin_amdgcn_mfma_f32_16x16x32_bf16(qf[1][ks], kf, s[1][jn], 0, 0, 0);
      }

    // ---- scale + causal mask (only diagonal tile needs the compare) ----
    const bool diag = (kt == qt);
#pragma unroll
    for (int im = 0; im < 2; im++)
#pragma unroll
      for (int jn = 0; jn < 8; jn++)
#pragma unroll
        for (int r = 0; r < 4; r++) {
          float x = s[im][jn][r] * 0.125f;
          if (diag && (jn * 16 + l16 > wave * 32 + im * 16 + quad * 4 + r)) x = -3e38f;
          s[im][jn][r] = x;
        }

    // ---- online softmax (row reductions across the 16 lanes of a quad) ----
    float alpha[2][4];
#pragma unroll
    for (int im = 0; im < 2; im++)
#pragma unroll
      for (int r = 0; r < 4; r++) {
        float mt = s[im][0][r];
#pragma unroll
        for (int jn = 1; jn < 8; jn++) mt = fmaxf(mt, s[im][jn][r]);
        mt = fmaxf(mt, __shfl_xor(mt, 1));
        mt = fmaxf(mt, __shfl_xor(mt, 2));
        mt = fmaxf(mt, __shfl_xor(mt, 4));
        mt = fmaxf(mt, __shfl_xor(mt, 8));
        float mn = fmaxf(m_run[im][r], mt);
        float al = __expf(m_run[im][r] - mn);
        m_run[im][r] = mn;
        float rs = 0.f;
#pragma unroll
        for (int jn = 0; jn < 8; jn++) {
          float p = __expf(s[im][jn][r] - mn);
          s[im][jn][r] = p;
          rs += p;
        }
        rs += __shfl_xor(rs, 1); rs += __shfl_xor(rs, 2);
        rs += __shfl_xor(rs, 4); rs += __shfl_xor(rs, 8);
        l_run[im][r] = al * l_run[im][r] + rs;
        alpha[im][r] = al;
      }
#pragma unroll
    for (int im = 0; im < 2; im++)
#pragma unroll
      for (int jd = 0; jd < 4; jd++)
#pragma unroll
        for (int r = 0; r < 4; r++) o[im][jd][r] *= alpha[im][r];

    // ---- write P (wave-private rows; swizzled chunks) ----
#pragma unroll
    for (int im = 0; im < 2; im++)
#pragma unroll
      for (int jn = 0; jn < 8; jn++)
#pragma unroll
        for (int r = 0; r < 4; r++) {
          int row = wave * 32 + im * 16 + quad * 4 + r;
          int col = jn * 16 + l16;
          Ps[row * 128 + (((col >> 3) ^ (row & 7)) << 3) + (col & 7)] = f2bf(s[im][jn][r]);
        }
    // wave-private P: no barrier; drain lgkm so ds_reads see the writes
    __builtin_amdgcn_s_waitcnt(0xc07f);   // lgkmcnt(0), vmcnt/expcnt untouched

    // ---- O += P V ----
#pragma unroll
    for (int ks = 0; ks < 4; ks++) {
      bf16x8 pf[2];
#pragma unroll
      for (int im = 0; im < 2; im++) {
        int row = wave * 32 + im * 16 + l16;
        int c = (ks * 4 + quad) ^ (row & 7);
        pf[im] = *(const bf16x8*)&Ps[row * 128 + c * 8];
      }
#pragma unroll
      for (int jd = 0; jd < 4; jd++) {
        int dd = jd * 16 + l16;
        int c = (ks * 4 + quad) ^ (dd & 15);
        bf16x8 vf = *(const bf16x8*)&VT[dd * 128 + c * 8];
        o[0][jd] = __builtin_amdgcn_mfma_f32_16x16x32_bf16(pf[0], vf, o[0][jd], 0, 0, 0);
        o[1][jd] = __builtin_amdgcn_mfma_f32_16x16x32_bf16(pf[1], vf, o[1][jd], 0, 0, 0);
      }
    }
  }

  // ---- epilogue: O /= l, store bf16 to attn (T x 2048, col = h*64+d) ----
#pragma unroll
  for (int im = 0; im < 2; im++)
#pragma unroll
    for (int r = 0; r < 4; r++) {
      float inv = 1.0f / l_run[im][r];
      int t = qt * 128 + wave * 32 + im * 16 + quad * 4 + r;
      size_t rowOff = (tokBase + t) * 2048 + qcol;
#pragma unroll
      for (int jd = 0; jd < 4; jd++)
        attn[rowOff + jd * 16 + l16] = f2bf(o[im][jd][r] * inv);
    }
}

// ---------------- launch ----------------
extern "C" void kernel_launch(void* const* d_in, const int* in_sizes, int n_in,
                              void* d_out, int out_size, void* d_ws, size_t ws_size,
                              hipStream_t stream) {
  const float* hs = (const float*)d_in[0];
  const float* cs = (const float*)d_in[1];
  const float* sn = (const float*)d_in[2];
  const float* Wq = (const float*)d_in[3];
  const float* Wk = (const float*)d_in[4];
  const float* Wv = (const float*)d_in[5];
  const float* Wo = (const float*)d_in[6];
  float* out = (float*)d_out;

  char* ws = (char*)d_ws;
  u16* hsB   = (u16*)(ws);                  // 4096x2048 bf16        (16.78 MB)
  u16* wqkvT = (u16*)(ws + 16777216);       // 3072x2048 bf16 [WqT;WkT;WvT]
  u16* woT   = (u16*)(ws + 29360128);       // 2048x2048 bf16
  u16* qkv   = (u16*)(ws + 37748736);       // 4096x3072 bf16
  u16* attnB = (u16*)(ws + 62914560);       // 4096x2048 bf16  (total ~76 MB)

  convert_f32_bf16<<<8192, 256, 0, stream>>>(hs, hsB, 4096 * 2048 / 4);
  trans_f32_bf16<<<dim3(64, 64), 256, 0, stream>>>(Wq, wqkvT, 2048, 2048);
  trans_f32_bf16<<<dim3(16, 64), 256, 0, stream>>>(Wk, wqkvT + (size_t)2048 * 2048, 2048, 512);
  trans_f32_bf16<<<dim3(16, 64), 256, 0, stream>>>(Wv, wqkvT + (size_t)2560 * 2048, 2048, 512);
  trans_f32_bf16<<<dim3(64, 64), 256, 0, stream>>>(Wo, woT, 2048, 2048);

  gemm_bt<u16><<<dim3(3072 / 128, 4096 / 128), 256, 0, stream>>>(hsB, wqkvT, qkv, 4096, 3072, 2048);
  rope_k<<<20480, 256, 0, stream>>>(qkv, cs, sn);
  flash_attn<<<dim3(8, 32, 4), 256, 0, stream>>>(qkv, attnB);
  gemm_bt<float><<<dim3(2048 / 128, 4096 / 128), 256, 0, stream>>>(attnB, woT, out, 4096, 2048, 2048);
}